// Round 3
// baseline (109.391 us; speedup 1.0000x reference)
//
#include <hip/hip_runtime.h>

#pragma clang fp contract(off)

#define NP 410881  // 641*641

// ---------------------------------------------------------------------------
// Fused kernel, round 6.
// Round-5 post-mortem: 51.9us, VALUBusy 36%, occ 26% -> latency-bound.
// Cause 1: redundant slot scan was UNCOALESCED (thread t <-> row t, stride
//   536B): every 8B wave load = 64 cache lines. Fix: cooperative scan, each
//   wave reduces 2 rows/iter (32-lane halves over columns + 5-stage
//   shfl_xor butterfly, first-index tie-break).
// Cause 2: only 2 waves/block, 3.3 waves/SIMD; 128-deep channel chain.
//   Fix: 256-thread blocks; threads t / t+128 share a pixel pair and split
//   channels 0-63 / 64-127; LDS merge. 2x waves, half the serial chain.
// ---------------------------------------------------------------------------
__global__ __launch_bounds__(256) void fused_kernel(
    const float* __restrict__ logits, const float* __restrict__ probs,
    float* __restrict__ out) {
#pragma clang fp contract(off)
  __shared__ float tex[25 * 132];
  __shared__ float s_cls[128];
  __shared__ unsigned s_mchunk[4];
  __shared__ float s_pf[6 * 128];
  __shared__ int s_pai[2 * 128];

  int tid = threadIdx.x;
  int lane = tid & 63, wv = tid >> 6;
  int lt = tid & 127;   // pixel-pair id (two threads per pair)
  int half = tid >> 7;  // 0: channels 0-63, 1: channels 64-127
  int cbase = half << 6;

  int X0 = blockIdx.x << 4, Y0 = blockIdx.y << 4;
  int strip = lt & 7, py = lt >> 3;
  int cx = strip >> 1, h = strip & 1;
  int cy = py >> 2;
  int xa = X0 + (cx << 2) + (h << 1);
  int y = Y0 + py;

  // ---- A. issue tex global loads early (HBM); LDS writes deferred ----
  int tX = blockIdx.x << 2, tY = blockIdx.y << 2;  // texel origin
  float4 stg[4];
#pragma unroll
  for (int k = 0; k < 4; ++k) {
    int f = tid + (k << 8);
    if (f < 800) {  // 800 float4 granules = 5x5 texels x 128 ch
      int r = f / 160;
      int i = f - r * 160;
      int cc = i >> 5, c4 = i & 31;
      int gy = min(tY + r, 160);
      int gx = min(tX + cc, 160);
      stg[k] = *(const float4*)(logits + ((gy * 161 + gx) << 7) + (c4 << 2));
    }
  }

  // ---- B. slot tables, cooperative & coalesced (overlaps tex latency) ----
  // Wave wv owns rows 32wv..32wv+31; 2 rows per iteration via 32-lane
  // halves. Half-lane l5 covers cols 4*l5..4*l5+3 (+ leftover 128..132 for
  // l5<3; col 133 excluded). 5-stage butterfly, (max, first-index).
  {
    unsigned wmask = 0;
    int hl = lane >> 5;  // row-of-pair
    int l5 = lane & 31;
#pragma unroll 4
    for (int k = 0; k < 16; ++k) {
      int r = (wv << 5) + (k << 1) + hl;
      const float2* rp = (const float2*)(probs + r * 134);  // 8B-aligned
      float2 v1 = rp[2 * l5];
      float2 v2 = rp[2 * l5 + 1];
      float2 w = make_float2(-INFINITY, -INFINITY);
      if (l5 < 3) w = rp[64 + l5];
      if (l5 == 2) w.y = -INFINITY;  // col 133 excluded (probs[:, :-1])
      float bv = v1.x;
      int bi = 4 * l5;
      if (v1.y > bv) { bv = v1.y; bi = 4 * l5 + 1; }
      if (v2.x > bv) { bv = v2.x; bi = 4 * l5 + 2; }
      if (v2.y > bv) { bv = v2.y; bi = 4 * l5 + 3; }
      if (w.x > bv) { bv = w.x; bi = 128 + 2 * l5; }
      if (w.y > bv) { bv = w.y; bi = 129 + 2 * l5; }
#pragma unroll
      for (int off = 1; off <= 16; off <<= 1) {  // within 32-lane half
        float ov = __shfl_xor(bv, off);
        int oi = __shfl_xor(bi, off);
        if (ov > bv || (ov == bv && oi < bi)) { bv = ov; bi = oi; }
      }
      if (l5 == 0) s_cls[r] = (float)bi;
      wmask |= (bv >= 0.7f ? 1u : 0u) << ((k << 1) + hl);
    }
    unsigned other = __shfl(wmask, 32);  // odd-row bits live in lanes 32-63
    if (lane == 0) s_mchunk[wv] = wmask | other;
  }

  // ---- C. complete the LDS staging (transposed to [cell][132]) ----
#pragma unroll
  for (int k = 0; k < 4; ++k) {
    int f = tid + (k << 8);
    if (f < 800) {
      int r = f / 160;
      int i = f - r * 160;
      int cc = i >> 5, c4 = i & 31;
      *(float4*)(tex + (r * 5 + cc) * 132 + (c4 << 2)) = stg[k];
    }
  }
  __syncthreads();

  unsigned long long mlo =
      s_mchunk[0] | ((unsigned long long)s_mchunk[1] << 32);
  unsigned long long mhi =
      s_mchunk[2] | ((unsigned long long)s_mchunk[3] << 32);
  int ndet = __popcll(mlo) + __popcll(mhi);  // uniform

  if (ndet == 0) {  // reference zeroes everything when nothing detected
    if (half == 0 && y < 641) {
      if (xa < 641) {
        int i0 = y * 641 + xa;
        out[i0] = 1.0f; out[NP + i0] = 0.f; out[2 * NP + i0] = 0.f; out[3 * NP + i0] = 0.f;
      }
      if (xa + 1 < 641) {
        int i1 = y * 641 + xa + 1;
        out[i1] = 1.0f; out[NP + i1] = 0.f; out[2 * NP + i1] = 0.f; out[3 * NP + i1] = 0.f;
      }
    }
    return;
  }

  const float* p0 = tex + (cy * 5 + cx) * 132 + cbase;  // a00/a01 rows
  const float* p1 = p0 + 5 * 132;                       // a10/a11 rows
  float wy = 0.25f * (float)(py & 3);
  float iwy = 1.0f - wy;
  float wx0 = 0.5f * (float)h;
  float wx1 = wx0 + 0.25f;
  float iwx0 = 1.0f - wx0, iwx1 = 1.0f - wx1;

  float m0 = -INFINITY, m1 = -INFINITY;  // half-local masked max
  int am0 = cbase, am1 = cbase;          // half-local masked argmax
  float T0 = 0.f, T1 = 0.f;              // half-local sum exp over detected
  float rm0 = -INFINITY, rm1 = -INFINITY;  // half-local raw max

  if (ndet == 128) {  // fast path: masked == resized
    // 4 independent accumulator streams: stream j = channels c with c&3==j
    float ms0[4], ms1[4], Ts0[4], Ts1[4];
    int as0[4], as1[4];
#pragma unroll
    for (int j = 0; j < 4; ++j) {
      ms0[j] = -INFINITY; ms1[j] = -INFINITY;
      Ts0[j] = 0.f; Ts1[j] = 0.f;
      as0[j] = cbase + j; as1[j] = cbase + j;
    }
// one channel into stream J; reference op order, contract off
#define CH(A00, A01, A10, A11, CIDX, J)                                        \
  {                                                                            \
    float r0 = (A00) * iwy + (A10) * wy;                                       \
    float r1 = (A01) * iwy + (A11) * wy;                                       \
    float v0 = r0 * iwx0 + r1 * wx0;                                           \
    float v1 = r0 * iwx1 + r1 * wx1;                                           \
    bool g0 = v0 > ms0[J]; ms0[J] = g0 ? v0 : ms0[J]; as0[J] = g0 ? (CIDX) : as0[J]; \
    bool g1 = v1 > ms1[J]; ms1[J] = g1 ? v1 : ms1[J]; as1[J] = g1 ? (CIDX) : as1[J]; \
    Ts0[J] += __expf(v0);                                                      \
    Ts1[J] += __expf(v1);                                                      \
  }
#pragma unroll 2
    for (int c = 0; c < 64; c += 4) {
      float4 q00 = *(const float4*)(p0 + c);
      float4 q01 = *(const float4*)(p0 + c + 132);
      float4 q10 = *(const float4*)(p1 + c);
      float4 q11 = *(const float4*)(p1 + c + 132);
      CH(q00.x, q01.x, q10.x, q11.x, cbase + c + 0, 0);
      CH(q00.y, q01.y, q10.y, q11.y, cbase + c + 1, 1);
      CH(q00.z, q01.z, q10.z, q11.z, cbase + c + 2, 2);
      CH(q00.w, q01.w, q10.w, q11.w, cbase + c + 3, 3);
    }
#undef CH
    // exact merge: max; on value tie, smallest channel index wins
    m0 = ms0[0]; am0 = as0[0]; m1 = ms1[0]; am1 = as1[0];
#pragma unroll
    for (int j = 1; j < 4; ++j) {
      if (ms0[j] > m0 || (ms0[j] == m0 && as0[j] < am0)) { m0 = ms0[j]; am0 = as0[j]; }
      if (ms1[j] > m1 || (ms1[j] == m1 && as1[j] < am1)) { m1 = ms1[j]; am1 = as1[j]; }
    }
    T0 = (Ts0[0] + Ts0[1]) + (Ts0[2] + Ts0[3]);
    T1 = (Ts1[0] + Ts1[1]) + (Ts1[2] + Ts1[3]);
    rm0 = m0; rm1 = m1;  // raw == masked when all detected
  } else {  // general: separate raw max; per-channel detection is uniform
    unsigned long long mm = half ? mhi : mlo;
#pragma unroll 4
    for (int c = 0; c < 64; ++c) {
      float a00 = p0[c], a01 = p0[c + 132];
      float a10 = p1[c], a11 = p1[c + 132];
      float r0 = a00 * iwy + a10 * wy;
      float r1 = a01 * iwy + a11 * wy;
      float v0 = r0 * iwx0 + r1 * wx0;
      float v1 = r0 * iwx1 + r1 * wx1;
      rm0 = fmaxf(rm0, v0);
      rm1 = fmaxf(rm1, v1);
      if ((mm >> c) & 1) {  // wave-uniform branch
        bool g0 = v0 > m0; m0 = g0 ? v0 : m0; am0 = g0 ? cbase + c : am0;
        bool g1 = v1 > m1; m1 = g1 ? v1 : m1; am1 = g1 ? cbase + c : am1;
        T0 += __expf(v0);
        T1 += __expf(v1);
      }
    }
  }

  // ---- cross-half merge via LDS ----
  if (half) {
    s_pf[0 * 128 + lt] = m0; s_pf[1 * 128 + lt] = T0; s_pf[2 * 128 + lt] = rm0;
    s_pf[3 * 128 + lt] = m1; s_pf[4 * 128 + lt] = T1; s_pf[5 * 128 + lt] = rm1;
    s_pai[lt] = am0; s_pai[128 + lt] = am1;
  }
  __syncthreads();
  if (half) return;

  {
    float mh0 = s_pf[0 * 128 + lt], Th0 = s_pf[1 * 128 + lt], rh0 = s_pf[2 * 128 + lt];
    float mh1 = s_pf[3 * 128 + lt], Th1 = s_pf[4 * 128 + lt], rh1 = s_pf[5 * 128 + lt];
    int ah0 = s_pai[lt], ah1 = s_pai[128 + lt];
    // strict >: all hi indices > lo indices, so ties keep lo (first index)
    if (mh0 > m0) { m0 = mh0; am0 = ah0; }
    if (mh1 > m1) { m1 = mh1; am1 = ah1; }
    rm0 = fmaxf(rm0, rh0); rm1 = fmaxf(rm1, rh1);
    T0 += Th0; T1 += Th1;
  }
  bool dp0 = (rm0 == m0), dp1 = (rm1 == m1);

  // ---- epilogue: conf > 0.4  <=>  exp(m) > 0.4*T  (T > 0, all v bounded)
  float cg0 = ((__expf(m0) > 0.4f * T0) && dp0) ? 1.0f : 0.0f;
  float cg1 = ((__expf(m1) > 0.4f * T1) && dp1) ? 1.0f : 0.0f;
  float sem0 = s_cls[am0], sem1 = s_cls[am1];

  // mask_id_map_plus_one = inclusive-cumsum(detected)[am]
  float mid0, mid1;
  if (ndet == 128) {
    mid0 = (float)(am0 + 1);
    mid1 = (float)(am1 + 1);
  } else {
    int a = am0;
    unsigned long long ml = (a >= 63) ? mlo : (mlo & ((1ull << (a + 1)) - 1));
    int cnt = __popcll(ml);
    if (a >= 64) {
      unsigned long long mh = (a >= 127) ? mhi : (mhi & ((1ull << (a - 63)) - 1));
      cnt += __popcll(mh);
    }
    mid0 = (float)cnt;
    a = am1;
    ml = (a >= 63) ? mlo : (mlo & ((1ull << (a + 1)) - 1));
    cnt = __popcll(ml);
    if (a >= 64) {
      unsigned long long mh = (a >= 127) ? mhi : (mhi & ((1ull << (a - 63)) - 1));
      cnt += __popcll(mh);
    }
    mid1 = (float)cnt;
  }

  float th0 = (sem0 < 80.f) ? cg0 : 0.f;
  float st0 = cg0 - th0;
  float th1 = (sem1 < 80.f) ? cg1 : 0.f;
  float st1 = cg1 - th1;

  if (y < 641) {
    if (xa < 641) {
      int i0 = y * 641 + xa;
      out[i0] = mid0; out[NP + i0] = sem0; out[2 * NP + i0] = th0; out[3 * NP + i0] = st0;
    }
    if (xa + 1 < 641) {
      int i1 = y * 641 + xa + 1;
      out[i1] = mid1; out[NP + i1] = sem1; out[2 * NP + i1] = th1; out[3 * NP + i1] = st1;
    }
  }
}

extern "C" void kernel_launch(void* const* d_in, const int* in_sizes, int n_in,
                              void* d_out, int out_size, void* d_ws,
                              size_t ws_size, hipStream_t stream) {
  const float* logits = (const float*)d_in[0];  // (161,161,128) f32
  const float* probs = (const float*)d_in[1];   // (128,134) f32
  float* out = (float*)d_out;
  (void)d_ws; (void)ws_size;

  dim3 grid(41, 41);
  fused_kernel<<<grid, 256, 0, stream>>>(logits, probs, out);
}

// Round 6
// 93.165 us; speedup vs baseline: 1.1742x; 1.1742x over previous
//
#include <hip/hip_runtime.h>

#pragma clang fp contract(off)

#define NP 410881  // 641*641

// ---------------------------------------------------------------------------
// Kernel 1: per-slot tables from transformer_class_probs (128 x 134).
// One wave per 8 rows; shuffle-reduce (max, first-index) over 133 cols.
// (Round-1 version, proven absmax=0.)
// ---------------------------------------------------------------------------
__global__ __launch_bounds__(1024) void slot_kernel(
    const float* __restrict__ probs, float* __restrict__ cls_pred,
    int* __restrict__ det_idx, unsigned long long* __restrict__ det_mask,
    int* __restrict__ num_det) {
  __shared__ float s_val[128];
  __shared__ int s_arg[128];
  __shared__ int s_tot0;
  int tid = threadIdx.x;
  int wv = tid >> 6, lane = tid & 63;

  float bvv[8];
  int bii[8];
#pragma unroll
  for (int k = 0; k < 8; ++k) {
    int r = wv * 8 + k;
    const float* row = probs + r * 134;
    float v0 = row[lane];
    float v1 = row[lane + 64];
    float v2 = (lane < 5) ? row[lane + 128] : -1.0f;
    float bv = v0;
    int bi = lane;
    if (v1 > bv) { bv = v1; bi = lane + 64; }
    if (v2 > bv) { bv = v2; bi = lane + 128; }
    bvv[k] = bv; bii[k] = bi;
  }
#pragma unroll
  for (int k = 0; k < 8; ++k) {
    float bv = bvv[k];
    int bi = bii[k];
#pragma unroll
    for (int off = 32; off; off >>= 1) {  // (max, first-idx) butterfly
      float ov = __shfl_xor(bv, off);
      int oi = __shfl_xor(bi, off);
      if (ov > bv || (ov == bv && oi < bi)) { bv = ov; bi = oi; }
    }
    if (lane == 0) { s_val[wv * 8 + k] = bv; s_arg[wv * 8 + k] = bi; }
  }
  __syncthreads();

  bool flag = false;
  unsigned long long b = 0;
  if (tid < 128) flag = s_val[tid] >= 0.7f;
  if (wv < 2) b = __ballot(flag);  // wave-uniform branch
  if (tid < 128 && lane == 0) {
    det_mask[wv] = b;
    if (wv == 0) s_tot0 = __popcll(b);
  }
  __syncthreads();
  if (tid < 128) {
    int incl = __popcll(b & ((1ull << lane) - 1)) + (flag ? 1 : 0) +
               (wv ? s_tot0 : 0);
    det_idx[tid] = incl - 1;  // cumsum(det)-1
    cls_pred[tid] = (float)s_arg[tid];
    if (tid == 127) *num_det = incl;
  }
}

// ---------------------------------------------------------------------------
// Kernel 2, round 8. = round-7 structure with the exp2 novelty stripped
// (r7 failed twice; the only never-run construct was the exp2 path — this
// uses __expf, proven absmax=0 in rounds 1-3). Structure vs 95us baseline:
//  - 32x16 px tile (grid 21x41), 512 threads: 256 pixel-pairs x 2 channel
//    halves (thread t / t+256 split channels 0-63 / 64-127, LDS merge —
//    merge semantics proven correct in round-3's passing bench).
//    2x waves/SIMD (3.3 -> 6.7) against the latency exposure (r2: busy 36%
//    at occ 26%).
//  - Wave = 4 full 32-px rows -> 128 B contiguous stores per plane per row
//    (r1-r3 wrote 64 B chunks: WRITE_SIZE 30 MB vs 6.6 MB ideal).
// ---------------------------------------------------------------------------
__global__ __launch_bounds__(512) void post_kernel(
    const float* __restrict__ logits, const float* __restrict__ ws_cls,
    const int* __restrict__ ws_didx,
    const unsigned long long* __restrict__ ws_mask,
    const int* __restrict__ ws_ndet, float* __restrict__ out) {
#pragma clang fp contract(off)
  __shared__ float tex[45 * 132];   // 5y x 9x texels x 132 (pad) = 23.8 KB
  __shared__ float s_cls[128];
  __shared__ int s_didx[128];
  __shared__ float s_pf[6 * 256];
  __shared__ int s_pai[2 * 256];

  int tid = threadIdx.x;
  int lt = tid & 255;   // pixel-pair id
  int half = tid >> 8;  // 0: channels 0-63, 1: channels 64-127
  int cbase = half << 6;

  int X0 = blockIdx.x << 5, Y0 = blockIdx.y << 4;
  int strip = lt & 15, py = lt >> 4;
  int cx = strip >> 1, h = strip & 1;
  int cy = py >> 2;
  int xa = X0 + (cx << 2) + (h << 1);
  int y = Y0 + py;

  int ndet = *ws_ndet;  // uniform
  if (ndet == 0) {      // reference zeroes everything when nothing detected
    if (half == 0 && y < 641) {
      if (xa < 641) {
        int i0 = y * 641 + xa;
        out[i0] = 1.0f; out[NP + i0] = 0.f; out[2 * NP + i0] = 0.f; out[3 * NP + i0] = 0.f;
      }
      if (xa + 1 < 641) {
        int i1 = y * 641 + xa + 1;
        out[i1] = 1.0f; out[NP + i1] = 0.f; out[2 * NP + i1] = 0.f; out[3 * NP + i1] = 0.f;
      }
    }
    return;
  }

  // ---- stage 5y x 9x texels x 128 ch into LDS (transposed, padded) ----
  int tX = blockIdx.x << 3, tY = blockIdx.y << 2;  // texel origin
#pragma unroll
  for (int k = 0; k < 3; ++k) {
    int f = tid + (k << 9);
    if (f < 1440) {  // 1440 float4 granules = 45 texels x 32
      int r = f / 288;           // y-texel 0..4
      int i = f - r * 288;
      int cc = i >> 5, c4 = i & 31;  // x-texel 0..8, float4 id
      int gy = min(tY + r, 160);
      int gx = min(tX + cc, 160);
      float4 v = *(const float4*)(logits + ((gy * 161 + gx) << 7) + (c4 << 2));
      *(float4*)(tex + (r * 9 + cc) * 132 + (c4 << 2)) = v;
    }
  }
  if (tid < 128) {
    s_cls[tid] = ws_cls[tid];
    s_didx[tid] = ws_didx[tid];
  }
  __syncthreads();

  unsigned long long mlo = ws_mask[0], mhi = ws_mask[1];

  const float* p0 = tex + (cy * 9 + cx) * 132 + cbase;  // a00; a01 @ +132
  const float* p1 = p0 + 9 * 132;                       // a10; a11 @ +132
  float wy = 0.25f * (float)(py & 3);
  float iwy = 1.0f - wy;
  float wx0 = 0.5f * (float)h;
  float wx1 = wx0 + 0.25f;
  float iwx0 = 1.0f - wx0, iwx1 = 1.0f - wx1;

  float m0 = -INFINITY, m1 = -INFINITY;    // half-local masked max
  int am0 = cbase, am1 = cbase;            // half-local masked argmax
  float T0 = 0.f, T1 = 0.f;                // half-local sum exp over detected
  float rm0 = -INFINITY, rm1 = -INFINITY;  // half-local raw max

  if (ndet == 128) {  // fast path: masked == resized
    // 4 independent accumulator streams: stream j = channels c with c&3==j
    float ms0[4], ms1[4], Ts0[4], Ts1[4];
    int as0[4], as1[4];
#pragma unroll
    for (int j = 0; j < 4; ++j) {
      ms0[j] = -INFINITY; ms1[j] = -INFINITY;
      Ts0[j] = 0.f; Ts1[j] = 0.f;
      as0[j] = cbase + j; as1[j] = cbase + j;
    }
// one channel into stream J; reference op order, contract off
#define CH(A00, A01, A10, A11, CIDX, J)                                        \
  {                                                                            \
    float r0 = (A00) * iwy + (A10) * wy;                                       \
    float r1 = (A01) * iwy + (A11) * wy;                                       \
    float v0 = r0 * iwx0 + r1 * wx0;                                           \
    float v1 = r0 * iwx1 + r1 * wx1;                                           \
    bool g0 = v0 > ms0[J]; ms0[J] = g0 ? v0 : ms0[J]; as0[J] = g0 ? (CIDX) : as0[J]; \
    bool g1 = v1 > ms1[J]; ms1[J] = g1 ? v1 : ms1[J]; as1[J] = g1 ? (CIDX) : as1[J]; \
    Ts0[J] += __expf(v0);                                                      \
    Ts1[J] += __expf(v1);                                                      \
  }
#pragma unroll 2
    for (int c = 0; c < 64; c += 4) {
      float4 q00 = *(const float4*)(p0 + c);
      float4 q01 = *(const float4*)(p0 + c + 132);
      float4 q10 = *(const float4*)(p1 + c);
      float4 q11 = *(const float4*)(p1 + c + 132);
      CH(q00.x, q01.x, q10.x, q11.x, cbase + c + 0, 0);
      CH(q00.y, q01.y, q10.y, q11.y, cbase + c + 1, 1);
      CH(q00.z, q01.z, q10.z, q11.z, cbase + c + 2, 2);
      CH(q00.w, q01.w, q10.w, q11.w, cbase + c + 3, 3);
    }
#undef CH
    // exact merge: max; on value tie, smallest channel index wins
    m0 = ms0[0]; am0 = as0[0]; m1 = ms1[0]; am1 = as1[0];
#pragma unroll
    for (int j = 1; j < 4; ++j) {
      if (ms0[j] > m0 || (ms0[j] == m0 && as0[j] < am0)) { m0 = ms0[j]; am0 = as0[j]; }
      if (ms1[j] > m1 || (ms1[j] == m1 && as1[j] < am1)) { m1 = ms1[j]; am1 = as1[j]; }
    }
    T0 = (Ts0[0] + Ts0[1]) + (Ts0[2] + Ts0[3]);
    T1 = (Ts1[0] + Ts1[1]) + (Ts1[2] + Ts1[3]);
    rm0 = m0; rm1 = m1;  // raw == masked when all detected
  } else {  // general: separate raw max; per-channel detection is uniform
    unsigned long long mm = half ? mhi : mlo;
#pragma unroll 4
    for (int c = 0; c < 64; ++c) {
      float a00 = p0[c], a01 = p0[c + 132];
      float a10 = p1[c], a11 = p1[c + 132];
      float r0 = a00 * iwy + a10 * wy;
      float r1 = a01 * iwy + a11 * wy;
      float v0 = r0 * iwx0 + r1 * wx0;
      float v1 = r0 * iwx1 + r1 * wx1;
      rm0 = fmaxf(rm0, v0);
      rm1 = fmaxf(rm1, v1);
      if ((mm >> c) & 1) {  // wave-uniform branch
        bool g0 = v0 > m0; m0 = g0 ? v0 : m0; am0 = g0 ? cbase + c : am0;
        bool g1 = v1 > m1; m1 = g1 ? v1 : m1; am1 = g1 ? cbase + c : am1;
        T0 += __expf(v0);
        T1 += __expf(v1);
      }
    }
  }

  // ---- cross-half merge via LDS ----
  if (half) {
    s_pf[0 * 256 + lt] = m0; s_pf[1 * 256 + lt] = T0; s_pf[2 * 256 + lt] = rm0;
    s_pf[3 * 256 + lt] = m1; s_pf[4 * 256 + lt] = T1; s_pf[5 * 256 + lt] = rm1;
    s_pai[lt] = am0; s_pai[256 + lt] = am1;
  }
  __syncthreads();
  if (half) return;

  {
    float mh0 = s_pf[0 * 256 + lt], Th0 = s_pf[1 * 256 + lt], rh0 = s_pf[2 * 256 + lt];
    float mh1 = s_pf[3 * 256 + lt], Th1 = s_pf[4 * 256 + lt], rh1 = s_pf[5 * 256 + lt];
    int ah0 = s_pai[lt], ah1 = s_pai[256 + lt];
    // strict >: all hi indices > lo indices, so ties keep lo (first index)
    if (mh0 > m0) { m0 = mh0; am0 = ah0; }
    if (mh1 > m1) { m1 = mh1; am1 = ah1; }
    rm0 = fmaxf(rm0, rh0); rm1 = fmaxf(rm1, rh1);
    T0 += Th0; T1 += Th1;
  }
  bool dp0 = (rm0 == m0), dp1 = (rm1 == m1);

  // ---- epilogue: conf > 0.4  <=>  exp(m) > 0.4*T  (T > 0, all v bounded)
  float cg0 = ((__expf(m0) > 0.4f * T0) && dp0) ? 1.0f : 0.0f;
  float cg1 = ((__expf(m1) > 0.4f * T1) && dp1) ? 1.0f : 0.0f;
  float sem0 = s_cls[am0], sem1 = s_cls[am1];
  float mid0 = (float)(s_didx[am0] + 1), mid1 = (float)(s_didx[am1] + 1);
  float th0 = (sem0 < 80.f) ? cg0 : 0.f;
  float st0 = cg0 - th0;
  float th1 = (sem1 < 80.f) ? cg1 : 0.f;
  float st1 = cg1 - th1;

  if (y < 641) {
    if (xa < 641) {
      int i0 = y * 641 + xa;
      out[i0] = mid0; out[NP + i0] = sem0; out[2 * NP + i0] = th0; out[3 * NP + i0] = st0;
    }
    if (xa + 1 < 641) {
      int i1 = y * 641 + xa + 1;
      out[i1] = mid1; out[NP + i1] = sem1; out[2 * NP + i1] = th1; out[3 * NP + i1] = st1;
    }
  }
}

extern "C" void kernel_launch(void* const* d_in, const int* in_sizes, int n_in,
                              void* d_out, int out_size, void* d_ws,
                              size_t ws_size, hipStream_t stream) {
  const float* logits = (const float*)d_in[0];  // (161,161,128) f32
  const float* probs = (const float*)d_in[1];   // (128,134) f32
  float* out = (float*)d_out;

  float* ws_f = (float*)d_ws;
  float* cls_pred = ws_f;                                    // 128 f32
  int* det_idx = (int*)(ws_f + 128);                         // 128 i32
  unsigned long long* det_mask = (unsigned long long*)(ws_f + 256);  // 2 u64
  int* num_det = (int*)(ws_f + 260);                         // 1 i32

  slot_kernel<<<1, 1024, 0, stream>>>(probs, cls_pred, det_idx, det_mask,
                                      num_det);

  dim3 grid(21, 41);
  post_kernel<<<grid, 512, 0, stream>>>(logits, cls_pred, det_idx, det_mask,
                                        num_det, out);
}